// Round 19
// baseline (128.834 us; speedup 1.0000x reference)
//
#include <hip/hip_runtime.h>
#include <hip/hip_bf16.h>
#include <stdint.h>

#define LSEQ 2048
#define BATCH 2
#define DMODEL 1024
#define NH 16
#define HD 64

typedef __attribute__((ext_vector_type(8))) short bf16x8;
typedef __attribute__((ext_vector_type(4))) float f32x4;

__device__ __forceinline__ short f2bf(float f) {
  union { float f; uint32_t u; } v; v.f = f;
  uint32_t r = v.u + 0x8000u;
  return (short)(r >> 16);
}

// packed 2xfp32 -> 2xbf16 via HIP intrinsic (RNE; emits v_cvt_pk_bf16_f32)
__device__ __forceinline__ uint32_t pack_bf16(float lo, float hi) {
  __hip_bfloat162 hb = __float22bfloat162_rn(float2{lo, hi});
  union { __hip_bfloat162 h; uint32_t u; } cv; cv.h = hb;
  return cv.u;
}

__device__ __forceinline__ float exp2_fast(float x) {
#if __has_builtin(__builtin_amdgcn_exp2f)
  return __builtin_amdgcn_exp2f(x);
#else
  float r; asm("v_exp_f32 %0, %1" : "=v"(r) : "v"(x)); return r;
#endif
}

__device__ __forceinline__ void gll16(const void* g, void* l) {
  __builtin_amdgcn_global_load_lds(
      (const __attribute__((address_space(1))) void*)g,
      (__attribute__((address_space(3))) void*)l, 16, 0, 0);
}

// ---------------- fused prep: fp32->bf16 cvt of x, transpose+cvt of Wqkv/Wout ----------------
__global__ void prep_kernel(const float* __restrict__ x, const float* __restrict__ Wqkv,
                            const float* __restrict__ Wout, short* __restrict__ xbf,
                            short* __restrict__ wqkvT, short* __restrict__ woutT) {
  __shared__ float tile[32][33];
  const int bid = blockIdx.x;
  if (bid < 4096) {
    int i = (bid * 256 + threadIdx.x) * 4;
    float4 v = *(const float4*)(x + i);
    short4 o;
    o.x = f2bf(v.x); o.y = f2bf(v.y); o.z = f2bf(v.z); o.w = f2bf(v.w);
    *(short4*)(xbf + i) = o;
    return;
  }
  const float* in; short* out; int K, N, t;
  if (bid < 7168) { in = Wqkv; out = wqkvT; K = 1024; N = 3072; t = bid - 4096; }
  else            { in = Wout; out = woutT; K = 1024; N = 1024; t = bid - 7168; }
  int kb = (t & 31) * 32, nb = (t >> 5) * 32;
  int tx = threadIdx.x & 31, ty = threadIdx.x >> 5;
  #pragma unroll
  for (int i = ty; i < 32; i += 8)
    tile[i][tx] = in[(size_t)(kb + i) * N + nb + tx];
  __syncthreads();
  #pragma unroll
  for (int i = ty; i < 32; i += 8)
    out[(size_t)(nb + i) * K + kb + tx] = f2bf(tile[tx][i]);
}

// ---------------- 128x128 bf16 GEMM (qkv epilogue), Bt input [N][K], K=1024, BK=64 ----------------
__global__ __launch_bounds__(256, 2) void gemm_qkv(
    const short* __restrict__ A, const short* __restrict__ Bt,
    const float* __restrict__ bias,
    short* __restrict__ q_out, short* __restrict__ k_out, short* __restrict__ v_out) {
  constexpr int K = 1024, BK = 64, NKT = K / BK;
  __shared__ short Als[2][128 * BK];
  __shared__ short Bls[2][128 * BK];
  const int tid = threadIdx.x;
  const int lane = tid & 63;
  const int c = lane & 15, g = lane >> 4;
  const int m0 = blockIdx.x * 128;
  const int n0 = blockIdx.y * 128;
  const int wid = tid >> 6;
  const int wm = (wid >> 1) * 64, wn = (wid & 1) * 64;

  f32x4 acc[4][4] = {};

  auto stage = [&](int kt, int bbuf) {
    const int k0 = kt * BK;
    #pragma unroll
    for (int inst = 0; inst < 4; ++inst) {
      int i = inst * 256 + tid;
      int row = i >> 3, cg = i & 7;
      int scc = cg ^ (row & 7);
      gll16(A + (size_t)(m0 + row) * K + k0 + scc * 8, &Als[bbuf][i * 8]);
      gll16(Bt + (size_t)(n0 + row) * K + k0 + scc * 8, &Bls[bbuf][i * 8]);
    }
  };

  stage(0, 0);

  for (int kt = 0; kt < NKT; ++kt) {
    const int bb = kt & 1;
    asm volatile("s_waitcnt vmcnt(0)" ::: "memory");
    __builtin_amdgcn_s_barrier();
    if (kt < NKT - 1) stage(kt + 1, bb ^ 1);

    #pragma unroll
    for (int ks = 0; ks < 2; ++ks) {
      const int kb = ks * 64 + g * 16;
      bf16x8 af[4], bfv[4];
      #pragma unroll
      for (int m = 0; m < 4; ++m) {
        int row = wm + m * 16 + c;
        af[m] = *(const bf16x8*)((const char*)&Als[bb][0] + row * 128 + (kb ^ ((row & 7) << 4)));
      }
      #pragma unroll
      for (int n = 0; n < 4; ++n) {
        int row = wn + n * 16 + c;
        bfv[n] = *(const bf16x8*)((const char*)&Bls[bb][0] + row * 128 + (kb ^ ((row & 7) << 4)));
      }
      __builtin_amdgcn_s_setprio(1);
      #pragma unroll
      for (int m = 0; m < 4; ++m)
        #pragma unroll
        for (int n = 0; n < 4; ++n)
          acc[m][n] = __builtin_amdgcn_mfma_f32_16x16x32_bf16(af[m], bfv[n], acc[m][n], 0, 0, 0);
      __builtin_amdgcn_s_setprio(0);
    }
  }

  #pragma unroll
  for (int m = 0; m < 4; ++m) {
    #pragma unroll
    for (int n = 0; n < 4; ++n) {
      #pragma unroll
      for (int r = 0; r < 4; ++r) {
        int row = m0 + wm + m * 16 + g * 4 + r;
        int col = n0 + wn + n * 16 + c;
        float val = acc[m][n][r] + bias[col];
        int b = row >> 11, l = row & 2047;
        int which = col >> 10, rem = col & 1023;
        int hn = rem >> 6, d = rem & 63;
        size_t bh = (size_t)b * NH + hn;
        // 0.125 * log2(e): QK^T lands directly in exp2 domain
        if (which == 0)       q_out[(bh * LSEQ + l) * HD + d] = f2bf(val * 0.1803368801f);
        else if (which == 1)  k_out[(bh * LSEQ + l) * HD + d] = f2bf(val);
        else                  v_out[(bh * HD + d) * LSEQ + l] = f2bf(val);
      }
    }
  }
}

// ---------------- 128x64 bf16 GEMM (out-proj), doubled grid for occupancy ----------------
__global__ __launch_bounds__(256, 3) void gemm_out64(
    const short* __restrict__ A, const short* __restrict__ Bt,
    const float* __restrict__ bias, float* __restrict__ outf) {
  constexpr int K = 1024, BK = 64, NKT = K / BK;
  __shared__ short Als[2][128 * BK];
  __shared__ short Bls[2][64 * BK];
  const int tid = threadIdx.x;
  const int lane = tid & 63;
  const int c = lane & 15, g = lane >> 4;
  const int m0 = blockIdx.x * 128;
  const int n0 = blockIdx.y * 64;
  const int wid = tid >> 6;
  const int wm = (wid >> 1) * 64, wn = (wid & 1) * 32;

  f32x4 acc[4][2] = {};

  auto stage = [&](int kt, int bbuf) {
    const int k0 = kt * BK;
    #pragma unroll
    for (int inst = 0; inst < 4; ++inst) {
      int i = inst * 256 + tid;
      int row = i >> 3, cg = i & 7;
      int scc = cg ^ (row & 7);
      gll16(A + (size_t)(m0 + row) * K + k0 + scc * 8, &Als[bbuf][i * 8]);
      if (inst < 2)
        gll16(Bt + (size_t)(n0 + row) * K + k0 + scc * 8, &Bls[bbuf][i * 8]);
    }
  };

  stage(0, 0);

  for (int kt = 0; kt < NKT; ++kt) {
    const int bb = kt & 1;
    asm volatile("s_waitcnt vmcnt(0)" ::: "memory");
    __builtin_amdgcn_s_barrier();
    if (kt < NKT - 1) stage(kt + 1, bb ^ 1);

    #pragma unroll
    for (int ks = 0; ks < 2; ++ks) {
      const int kb = ks * 64 + g * 16;
      bf16x8 af[4], bfv[2];
      #pragma unroll
      for (int m = 0; m < 4; ++m) {
        int row = wm + m * 16 + c;
        af[m] = *(const bf16x8*)((const char*)&Als[bb][0] + row * 128 + (kb ^ ((row & 7) << 4)));
      }
      #pragma unroll
      for (int n = 0; n < 2; ++n) {
        int row = wn + n * 16 + c;
        bfv[n] = *(const bf16x8*)((const char*)&Bls[bb][0] + row * 128 + (kb ^ ((row & 7) << 4)));
      }
      __builtin_amdgcn_s_setprio(1);
      #pragma unroll
      for (int m = 0; m < 4; ++m)
        #pragma unroll
        for (int n = 0; n < 2; ++n)
          acc[m][n] = __builtin_amdgcn_mfma_f32_16x16x32_bf16(af[m], bfv[n], acc[m][n], 0, 0, 0);
      __builtin_amdgcn_s_setprio(0);
    }
  }

  #pragma unroll
  for (int m = 0; m < 4; ++m) {
    #pragma unroll
    for (int n = 0; n < 2; ++n) {
      #pragma unroll
      for (int r = 0; r < 4; ++r) {
        int row = m0 + wm + m * 16 + g * 4 + r;
        int col = n0 + wn + n * 16 + c;
        outf[(size_t)row * DMODEL + col] = acc[m][n][r] + bias[col];
      }
    }
  }
}

// ---------------- fused attention (cross-tile pipeline: QKT(t) || softmax+PV(t-1)) ----------------
// QBLK=128: 4 waves x 32 q-rows. K staged 1 tile ahead, V staged 0 ahead; PV
// consumes V(t-1) from the other dbuf half. Within an iteration QKT(t) and
// softmax/PV(t-1) are data-independent -> scheduler overlays VALU under MFMA.
__global__ __launch_bounds__(256, 2) void attn_kernel(
    const short* __restrict__ qb, const short* __restrict__ kb,
    const short* __restrict__ vtb, const unsigned char* __restrict__ kpm,
    const float* __restrict__ bias_table, short* __restrict__ ob) {
  constexpr int NT = LSEQ / 64;
  __shared__ short Kls[2][64 * 64];
  __shared__ short Vls[2][64 * 64];
  __shared__ uint2 Pls[4][512];
  __shared__ float biasc[257];
  __shared__ unsigned mbits_s;

  const int tid = threadIdx.x, lane = tid & 63, wid = tid >> 6;
  const int g = lane >> 4, c = lane & 15;
  const int lin = blockIdx.x;
  const int swz = (lin & 7) * 64 + (lin >> 3);
  const int q0 = (swz & 15) * 128;
  const int h = (swz >> 4) & 15;
  const int b = swz >> 8;
  const size_t bh = (size_t)b * NH + h;
  const short* qbase = qb + bh * LSEQ * HD;
  const short* kbase = kb + bh * LSEQ * HD;
  const short* vbase = vtb + bh * HD * LSEQ;
  const unsigned char* kpmb = kpm + (size_t)b * LSEQ;

  bf16x8 qf[2][2];
  #pragma unroll
  for (int qg = 0; qg < 2; ++qg)
    #pragma unroll
    for (int ks = 0; ks < 2; ++ks) {
      int qrow = q0 + wid * 32 + qg * 16 + c;
      qf[qg][ks] = *(const bf16x8*)(qbase + (size_t)qrow * HD + ks * 32 + g * 8);
    }

  if (tid < 32) {
    const uint4* mp = (const uint4*)(kpmb + tid * 64);
    uint4 m0 = mp[0], m1 = mp[1], m2 = mp[2], m3 = mp[3];
    unsigned anyb = m0.x | m0.y | m0.z | m0.w | m1.x | m1.y | m1.z | m1.w |
                    m2.x | m2.y | m2.z | m2.w | m3.x | m3.y | m3.z | m3.w;
    unsigned long long bal = __ballot(anyb != 0);
    if (tid == 0) mbits_s = (unsigned)bal;
  }
  for (int i = tid; i < 257; i += 256) biasc[i] = bias_table[i * NH + h] * 1.44269504f;
  __syncthreads();
  const unsigned mbits = mbits_s;
  const float cb_lo = biasc[0], cb_hi = biasc[256];

  auto stageK = [&](int t, int bbuf) {
    const int kv0s = t * 64;
    int row = tid >> 2, cc = tid & 3;   // 256 threads: rows 0..63, 4 cgs each... need 512 ops
    (void)row; (void)cc;
    #pragma unroll
    for (int inst = 0; inst < 2; ++inst) {
      int cc0 = inst * 256 + tid;
      int r2 = cc0 >> 3, cg = cc0 & 7;
      int scc = cg ^ (r2 & 7);
      gll16(kbase + (size_t)(kv0s + r2) * HD + scc * 8, &Kls[bbuf][cc0 * 8]);
    }
  };
  auto stageV = [&](int t, int bbuf) {
    const int kv0s = t * 64;
    #pragma unroll
    for (int inst = 0; inst < 2; ++inst) {
      int cc0 = inst * 256 + tid;
      int r2 = cc0 >> 3, cg = cc0 & 7;
      int scc = cg ^ (r2 & 7);
      gll16(vbase + (size_t)r2 * LSEQ + kv0s + scc * 8, &Vls[bbuf][cc0 * 8]);
    }
  };

  f32x4 o[4][2], l_acc[2];
  #pragma unroll
  for (int nt = 0; nt < 4; ++nt)
    #pragma unroll
    for (int qg = 0; qg < 2; ++qg) o[nt][qg] = (f32x4){0.f, 0.f, 0.f, 0.f};
  l_acc[0] = (f32x4){0.f, 0.f, 0.f, 0.f};
  l_acc[1] = (f32x4){0.f, 0.f, 0.f, 0.f};

  bf16x8 onesf;
  #pragma unroll
  for (int j = 0; j < 8; ++j) onesf[j] = (short)0x3F80;

  uint2* pw = &Pls[wid][0];
  const int c7s = (c & 7) << 4;
  const int cx  = (c & 7) << 1;

  f32x4 st_prev[4][2];

  // QKT for tile t from Kls[t&1] -> out[4][2]
  auto qkt = [&](int t, f32x4 out[4][2]) {
    const int bbk = t & 1;
    __builtin_amdgcn_s_setprio(1);
    #pragma unroll
    for (int nt = 0; nt < 4; ++nt) {
      f32x4 a0 = {}, a1 = {};
      #pragma unroll
      for (int ks = 0; ks < 2; ++ks) {
        int krow = nt * 16 + c;
        int kbyte = ks * 64 + g * 16;
        const bf16x8 kf =
            *(const bf16x8*)((const char*)&Kls[bbk][0] + krow * 128 + (kbyte ^ c7s));
        a0 = __builtin_amdgcn_mfma_f32_16x16x32_bf16(kf, qf[0][ks], a0, 0, 0, 0);
        a1 = __builtin_amdgcn_mfma_f32_16x16x32_bf16(kf, qf[1][ks], a1, 0, 0, 0);
      }
      out[nt][0] = a0; out[nt][1] = a1;
    }
    __builtin_amdgcn_s_setprio(0);
  };

  // softmax + P-write + PV for tile t using st_prev and Vls[t&1]
  auto smpv = [&](int t) {
    const int kv0 = t * 64;
    const int bbv = t & 1;
    const int dw = kv0 - q0 - wid * 32;
    if (dw >= 160 || dw <= -192) {
      const float cb = dw > 0 ? cb_hi : cb_lo;
      #pragma unroll
      for (int nt = 0; nt < 4; ++nt)
        #pragma unroll
        for (int qg = 0; qg < 2; ++qg)
          #pragma unroll
          for (int r = 0; r < 4; ++r) st_prev[nt][qg][r] += cb;
    } else {
      #pragma unroll
      for (int nt = 0; nt < 4; ++nt)
        #pragma unroll
        for (int qg = 0; qg < 2; ++qg) {
          const int base = dw + nt * 16 + g * 4 - qg * 16 - c;
          #pragma unroll
          for (int r = 0; r < 4; ++r) {
            int rel = base + r;
            rel = rel < -128 ? -128 : (rel > 128 ? 128 : rel);
            st_prev[nt][qg][r] += biasc[rel + 128];
          }
        }
    }
    if (mbits & (1u << t)) {
      #pragma unroll
      for (int nt = 0; nt < 4; ++nt)
        #pragma unroll
        for (int r = 0; r < 4; ++r) {
          float mk = kpmb[kv0 + nt * 16 + g * 4 + r] ? -1e30f : 0.f;
          st_prev[nt][0][r] += mk;
          st_prev[nt][1][r] += mk;
        }
    }

    #pragma unroll
    for (int qg = 0; qg < 2; ++qg)
      #pragma unroll
      for (int nt = 0; nt < 4; ++nt) {
        uint2 w;
        w.x = pack_bf16(exp2_fast(st_prev[nt][qg][0]), exp2_fast(st_prev[nt][qg][1]));
        w.y = pack_bf16(exp2_fast(st_prev[nt][qg][2]), exp2_fast(st_prev[nt][qg][3]));
        pw[(qg * 16 + c) * 16 + ((nt * 4 + g) ^ cx)] = w;
      }

    #pragma unroll
    for (int ks = 0; ks < 2; ++ks) {
      const int pu = (ks * 8 + g * 2) ^ cx;
      union { uint2 u[2]; bf16x8 v; } pa0u, pa1u;
      pa0u.u[0] = pw[c * 16 + pu];        pa0u.u[1] = pw[c * 16 + pu + 1];
      pa1u.u[0] = pw[(16 + c) * 16 + pu]; pa1u.u[1] = pw[(16 + c) * 16 + pu + 1];
      const bf16x8 pa0 = pa0u.v, pa1 = pa1u.v;
      l_acc[0] = __builtin_amdgcn_mfma_f32_16x16x32_bf16(pa0, onesf, l_acc[0], 0, 0, 0);
      l_acc[1] = __builtin_amdgcn_mfma_f32_16x16x32_bf16(pa1, onesf, l_acc[1], 0, 0, 0);
      const int pbyte = ks * 64 + g * 16;
      #pragma unroll
      for (int nt = 0; nt < 4; ++nt) {
        int vrow = nt * 16 + c;
        const bf16x8 vf =
            *(const bf16x8*)((const char*)&Vls[bbv][0] + vrow * 128 + (pbyte ^ c7s));
        o[nt][0] = __builtin_amdgcn_mfma_f32_16x16x32_bf16(pa0, vf, o[nt][0], 0, 0, 0);
        o[nt][1] = __builtin_amdgcn_mfma_f32_16x16x32_bf16(pa1, vf, o[nt][1], 0, 0, 0);
      }
    }
  };

  stageK(0, 0);

  for (int t = 0; t < NT; ++t) {
    asm volatile("s_waitcnt vmcnt(0)" ::: "memory");
    __builtin_amdgcn_s_barrier();
    if (t < NT - 1) stageK(t + 1, (t + 1) & 1);
    stageV(t, t & 1);

    f32x4 st_cur[4][2];
    qkt(t, st_cur);
    if (t > 0) smpv(t - 1);

    #pragma unroll
    for (int nt = 0; nt < 4; ++nt) {
      st_prev[nt][0] = st_cur[nt][0];
      st_prev[nt][1] = st_cur[nt][1];
    }
  }

  // epilogue: V(NT-1) landed after final stage; drain and finish last tile
  asm volatile("s_waitcnt vmcnt(0)" ::: "memory");
  __builtin_amdgcn_s_barrier();
  smpv(NT - 1);

  #pragma unroll
  for (int qg = 0; qg < 2; ++qg)
    #pragma unroll
    for (int r = 0; r < 4; ++r) {
      float inv = 1.f / l_acc[qg][r];
      int qrow = q0 + wid * 32 + qg * 16 + g * 4 + r;
      size_t obase = ((size_t)b * LSEQ + qrow) * DMODEL + (size_t)h * HD;
      #pragma unroll
      for (int nt = 0; nt < 4; ++nt)
        ob[obase + nt * 16 + c] = f2bf(o[nt][qg][r] * inv);
    }
}

extern "C" void kernel_launch(void* const* d_in, const int* in_sizes, int n_in,
                              void* d_out, int out_size, void* d_ws, size_t ws_size,
                              hipStream_t stream) {
  (void)in_sizes; (void)n_in; (void)out_size; (void)ws_size;
  const float* x = (const float*)d_in[0];
  const unsigned char* kpm = (const unsigned char*)d_in[1];
  const float* Wqkv = (const float*)d_in[2];
  const float* bqkv = (const float*)d_in[3];
  const float* Wout = (const float*)d_in[4];
  const float* bout = (const float*)d_in[5];
  const float* btab = (const float*)d_in[6];
  float* out = (float*)d_out;

  short* ws = (short*)d_ws;
  short* xbf   = ws;
  short* wqkvT = xbf + 4194304;
  short* woutT = wqkvT + 3145728;
  short* qbuf  = woutT + 1048576;
  short* kbuf  = qbuf + 4194304;
  short* vtbuf = kbuf + 4194304;
  short* obuf  = vtbuf + 4194304;

  prep_kernel<<<dim3(8192), dim3(256), 0, stream>>>(x, Wqkv, Wout, xbf, wqkvT, woutT);

  gemm_qkv<<<dim3(32, 24), dim3(256), 0, stream>>>(xbf, wqkvT, bqkv,
                                                   qbuf, kbuf, vtbuf);
  attn_kernel<<<dim3(512), dim3(256), 0, stream>>>(qbuf, kbuf, vtbuf, kpm, btab, obuf);
  gemm_out64<<<dim3(32, 16), dim3(256), 0, stream>>>(obuf, woutT, bout, out);
}

// Round 20
// 126.867 us; speedup vs baseline: 1.0155x; 1.0155x over previous
//
#include <hip/hip_runtime.h>
#include <hip/hip_bf16.h>
#include <stdint.h>

#define LSEQ 2048
#define BATCH 2
#define DMODEL 1024
#define NH 16
#define HD 64

typedef __attribute__((ext_vector_type(8))) short bf16x8;
typedef __attribute__((ext_vector_type(4))) float f32x4;

__device__ __forceinline__ short f2bf(float f) {
  union { float f; uint32_t u; } v; v.f = f;
  uint32_t r = v.u + 0x8000u;
  return (short)(r >> 16);
}

// packed 2xfp32 -> 2xbf16 via HIP intrinsic (RNE; emits v_cvt_pk_bf16_f32)
__device__ __forceinline__ uint32_t pack_bf16(float lo, float hi) {
  __hip_bfloat162 hb = __float22bfloat162_rn(float2{lo, hi});
  union { __hip_bfloat162 h; uint32_t u; } cv; cv.h = hb;
  return cv.u;
}

__device__ __forceinline__ float exp2_fast(float x) {
#if __has_builtin(__builtin_amdgcn_exp2f)
  return __builtin_amdgcn_exp2f(x);
#else
  float r; asm("v_exp_f32 %0, %1" : "=v"(r) : "v"(x)); return r;
#endif
}

__device__ __forceinline__ void gll16(const void* g, void* l) {
  __builtin_amdgcn_global_load_lds(
      (const __attribute__((address_space(1))) void*)g,
      (__attribute__((address_space(3))) void*)l, 16, 0, 0);
}

// ---------------- fused prep: fp32->bf16 cvt of x, transpose+cvt of Wqkv/Wout ----------------
__global__ void prep_kernel(const float* __restrict__ x, const float* __restrict__ Wqkv,
                            const float* __restrict__ Wout, short* __restrict__ xbf,
                            short* __restrict__ wqkvT, short* __restrict__ woutT) {
  __shared__ float tile[32][33];
  const int bid = blockIdx.x;
  if (bid < 4096) {
    int i = (bid * 256 + threadIdx.x) * 4;
    float4 v = *(const float4*)(x + i);
    short4 o;
    o.x = f2bf(v.x); o.y = f2bf(v.y); o.z = f2bf(v.z); o.w = f2bf(v.w);
    *(short4*)(xbf + i) = o;
    return;
  }
  const float* in; short* out; int K, N, t;
  if (bid < 7168) { in = Wqkv; out = wqkvT; K = 1024; N = 3072; t = bid - 4096; }
  else            { in = Wout; out = woutT; K = 1024; N = 1024; t = bid - 7168; }
  int kb = (t & 31) * 32, nb = (t >> 5) * 32;
  int tx = threadIdx.x & 31, ty = threadIdx.x >> 5;
  #pragma unroll
  for (int i = ty; i < 32; i += 8)
    tile[i][tx] = in[(size_t)(kb + i) * N + nb + tx];
  __syncthreads();
  #pragma unroll
  for (int i = ty; i < 32; i += 8)
    out[(size_t)(nb + i) * K + kb + tx] = f2bf(tile[tx][i]);
}

// ---------------- 128x64 bf16 GEMM (qkv epilogue), Bt input [N][K], K=1024, BK=64 ----------------
// 1536 blocks @ 3/CU = exactly 2 residency rounds, 12 waves/CU (tail-free).
__global__ __launch_bounds__(256, 3) void gemm_qkv64(
    const short* __restrict__ A, const short* __restrict__ Bt,
    const float* __restrict__ bias,
    short* __restrict__ q_out, short* __restrict__ k_out, short* __restrict__ v_out) {
  constexpr int K = 1024, BK = 64, NKT = K / BK;
  __shared__ short Als[2][128 * BK];
  __shared__ short Bls[2][64 * BK];
  const int tid = threadIdx.x;
  const int lane = tid & 63;
  const int c = lane & 15, g = lane >> 4;
  const int m0 = blockIdx.x * 128;
  const int n0 = blockIdx.y * 64;
  const int wid = tid >> 6;
  const int wm = (wid >> 1) * 64, wn = (wid & 1) * 32;

  f32x4 acc[4][2] = {};

  auto stage = [&](int kt, int bbuf) {
    const int k0 = kt * BK;
    #pragma unroll
    for (int inst = 0; inst < 4; ++inst) {
      int i = inst * 256 + tid;
      int row = i >> 3, cg = i & 7;
      int scc = cg ^ (row & 7);
      gll16(A + (size_t)(m0 + row) * K + k0 + scc * 8, &Als[bbuf][i * 8]);
      if (inst < 2)
        gll16(Bt + (size_t)(n0 + row) * K + k0 + scc * 8, &Bls[bbuf][i * 8]);
    }
  };

  stage(0, 0);

  for (int kt = 0; kt < NKT; ++kt) {
    const int bb = kt & 1;
    asm volatile("s_waitcnt vmcnt(0)" ::: "memory");
    __builtin_amdgcn_s_barrier();
    if (kt < NKT - 1) stage(kt + 1, bb ^ 1);

    #pragma unroll
    for (int ks = 0; ks < 2; ++ks) {
      const int kb = ks * 64 + g * 16;
      bf16x8 af[4], bfv[2];
      #pragma unroll
      for (int m = 0; m < 4; ++m) {
        int row = wm + m * 16 + c;
        af[m] = *(const bf16x8*)((const char*)&Als[bb][0] + row * 128 + (kb ^ ((row & 7) << 4)));
      }
      #pragma unroll
      for (int n = 0; n < 2; ++n) {
        int row = wn + n * 16 + c;
        bfv[n] = *(const bf16x8*)((const char*)&Bls[bb][0] + row * 128 + (kb ^ ((row & 7) << 4)));
      }
      __builtin_amdgcn_s_setprio(1);
      #pragma unroll
      for (int m = 0; m < 4; ++m)
        #pragma unroll
        for (int n = 0; n < 2; ++n)
          acc[m][n] = __builtin_amdgcn_mfma_f32_16x16x32_bf16(af[m], bfv[n], acc[m][n], 0, 0, 0);
      __builtin_amdgcn_s_setprio(0);
    }
  }

  #pragma unroll
  for (int m = 0; m < 4; ++m) {
    #pragma unroll
    for (int n = 0; n < 2; ++n) {
      #pragma unroll
      for (int r = 0; r < 4; ++r) {
        int row = m0 + wm + m * 16 + g * 4 + r;
        int col = n0 + wn + n * 16 + c;
        float val = acc[m][n][r] + bias[col];
        int b = row >> 11, l = row & 2047;
        int which = col >> 10, rem = col & 1023;
        int hn = rem >> 6, d = rem & 63;
        size_t bh = (size_t)b * NH + hn;
        // 0.125 * log2(e): QK^T lands directly in exp2 domain
        if (which == 0)       q_out[(bh * LSEQ + l) * HD + d] = f2bf(val * 0.1803368801f);
        else if (which == 1)  k_out[(bh * LSEQ + l) * HD + d] = f2bf(val);
        else                  v_out[(bh * HD + d) * LSEQ + l] = f2bf(val);
      }
    }
  }
}

// ---------------- 128x64 bf16 GEMM (out-proj) ----------------
__global__ __launch_bounds__(256, 3) void gemm_out64(
    const short* __restrict__ A, const short* __restrict__ Bt,
    const float* __restrict__ bias, float* __restrict__ outf) {
  constexpr int K = 1024, BK = 64, NKT = K / BK;
  __shared__ short Als[2][128 * BK];
  __shared__ short Bls[2][64 * BK];
  const int tid = threadIdx.x;
  const int lane = tid & 63;
  const int c = lane & 15, g = lane >> 4;
  const int m0 = blockIdx.x * 128;
  const int n0 = blockIdx.y * 64;
  const int wid = tid >> 6;
  const int wm = (wid >> 1) * 64, wn = (wid & 1) * 32;

  f32x4 acc[4][2] = {};

  auto stage = [&](int kt, int bbuf) {
    const int k0 = kt * BK;
    #pragma unroll
    for (int inst = 0; inst < 4; ++inst) {
      int i = inst * 256 + tid;
      int row = i >> 3, cg = i & 7;
      int scc = cg ^ (row & 7);
      gll16(A + (size_t)(m0 + row) * K + k0 + scc * 8, &Als[bbuf][i * 8]);
      if (inst < 2)
        gll16(Bt + (size_t)(n0 + row) * K + k0 + scc * 8, &Bls[bbuf][i * 8]);
    }
  };

  stage(0, 0);

  for (int kt = 0; kt < NKT; ++kt) {
    const int bb = kt & 1;
    asm volatile("s_waitcnt vmcnt(0)" ::: "memory");
    __builtin_amdgcn_s_barrier();
    if (kt < NKT - 1) stage(kt + 1, bb ^ 1);

    #pragma unroll
    for (int ks = 0; ks < 2; ++ks) {
      const int kb = ks * 64 + g * 16;
      bf16x8 af[4], bfv[2];
      #pragma unroll
      for (int m = 0; m < 4; ++m) {
        int row = wm + m * 16 + c;
        af[m] = *(const bf16x8*)((const char*)&Als[bb][0] + row * 128 + (kb ^ ((row & 7) << 4)));
      }
      #pragma unroll
      for (int n = 0; n < 2; ++n) {
        int row = wn + n * 16 + c;
        bfv[n] = *(const bf16x8*)((const char*)&Bls[bb][0] + row * 128 + (kb ^ ((row & 7) << 4)));
      }
      __builtin_amdgcn_s_setprio(1);
      #pragma unroll
      for (int m = 0; m < 4; ++m)
        #pragma unroll
        for (int n = 0; n < 2; ++n)
          acc[m][n] = __builtin_amdgcn_mfma_f32_16x16x32_bf16(af[m], bfv[n], acc[m][n], 0, 0, 0);
      __builtin_amdgcn_s_setprio(0);
    }
  }

  #pragma unroll
  for (int m = 0; m < 4; ++m) {
    #pragma unroll
    for (int n = 0; n < 2; ++n) {
      #pragma unroll
      for (int r = 0; r < 4; ++r) {
        int row = m0 + wm + m * 16 + g * 4 + r;
        int col = n0 + wn + n * 16 + c;
        outf[(size_t)row * DMODEL + col] = acc[m][n][r] + bias[col];
      }
    }
  }
}

// ---------------- fused attention ----------------
// QBLK=128: 4 waves x 32 q-rows. Canonical 2-phase. Swapped QK^T, no-max exp2
// softmax, l via ones-MFMA. Typed-uint2 P round-trip. XCD-swizzled 1D grid.
__global__ __launch_bounds__(256, 2) void attn_kernel(
    const short* __restrict__ qb, const short* __restrict__ kb,
    const short* __restrict__ vtb, const unsigned char* __restrict__ kpm,
    const float* __restrict__ bias_table, short* __restrict__ ob) {
  constexpr int NT = LSEQ / 64;
  __shared__ short Kls[2][64 * 64];
  __shared__ short Vls[2][64 * 64];
  __shared__ uint2 Pls[4][512];
  __shared__ float biasc[257];
  __shared__ unsigned mbits_s;

  const int tid = threadIdx.x, lane = tid & 63, wid = tid >> 6;
  const int g = lane >> 4, c = lane & 15;
  const int lin = blockIdx.x;
  const int swz = (lin & 7) * 64 + (lin >> 3);
  const int q0 = (swz & 15) * 128;
  const int h = (swz >> 4) & 15;
  const int b = swz >> 8;
  const size_t bh = (size_t)b * NH + h;
  const short* qbase = qb + bh * LSEQ * HD;
  const short* kbase = kb + bh * LSEQ * HD;
  const short* vbase = vtb + bh * HD * LSEQ;
  const unsigned char* kpmb = kpm + (size_t)b * LSEQ;

  bf16x8 qf[2][2];
  #pragma unroll
  for (int qg = 0; qg < 2; ++qg)
    #pragma unroll
    for (int ks = 0; ks < 2; ++ks) {
      int qrow = q0 + wid * 32 + qg * 16 + c;
      qf[qg][ks] = *(const bf16x8*)(qbase + (size_t)qrow * HD + ks * 32 + g * 8);
    }

  if (tid < 32) {
    const uint4* mp = (const uint4*)(kpmb + tid * 64);
    uint4 m0 = mp[0], m1 = mp[1], m2 = mp[2], m3 = mp[3];
    unsigned anyb = m0.x | m0.y | m0.z | m0.w | m1.x | m1.y | m1.z | m1.w |
                    m2.x | m2.y | m2.z | m2.w | m3.x | m3.y | m3.z | m3.w;
    unsigned long long bal = __ballot(anyb != 0);
    if (tid == 0) mbits_s = (unsigned)bal;
  }
  for (int i = tid; i < 257; i += 256) biasc[i] = bias_table[i * NH + h] * 1.44269504f;
  __syncthreads();
  const unsigned mbits = mbits_s;
  const float cb_lo = biasc[0], cb_hi = biasc[256];

  auto stage = [&](int t, int bbuf) {
    const int kv0s = t * 64;
    #pragma unroll
    for (int inst = 0; inst < 2; ++inst) {
      int cc0 = inst * 256 + tid;
      int row = cc0 >> 3, cc = cc0 & 7;
      int scc = cc ^ (row & 7);
      gll16(kbase + (size_t)(kv0s + row) * HD + scc * 8, &Kls[bbuf][cc0 * 8]);
      gll16(vbase + (size_t)row * LSEQ + kv0s + scc * 8, &Vls[bbuf][cc0 * 8]);
    }
  };

  f32x4 o[4][2], l_acc[2];
  #pragma unroll
  for (int nt = 0; nt < 4; ++nt)
    #pragma unroll
    for (int qg = 0; qg < 2; ++qg) o[nt][qg] = (f32x4){0.f, 0.f, 0.f, 0.f};
  l_acc[0] = (f32x4){0.f, 0.f, 0.f, 0.f};
  l_acc[1] = (f32x4){0.f, 0.f, 0.f, 0.f};

  bf16x8 onesf;
  #pragma unroll
  for (int j = 0; j < 8; ++j) onesf[j] = (short)0x3F80;

  uint2* pw = &Pls[wid][0];
  const int c7s = (c & 7) << 4;
  const int cx  = (c & 7) << 1;

  stage(0, 0);

  for (int t = 0; t < NT; ++t) {
    const int bb = t & 1;
    const int kv0 = t * 64;
    asm volatile("s_waitcnt vmcnt(0)" ::: "memory");
    __builtin_amdgcn_s_barrier();
    if (t < NT - 1) stage(t + 1, bb ^ 1);

    f32x4 st[4][2];
    __builtin_amdgcn_s_setprio(1);
    #pragma unroll
    for (int nt = 0; nt < 4; ++nt) {
      f32x4 a0 = {}, a1 = {};
      #pragma unroll
      for (int ks = 0; ks < 2; ++ks) {
        int krow = nt * 16 + c;
        int kbyte = ks * 64 + g * 16;
        const bf16x8 kf =
            *(const bf16x8*)((const char*)&Kls[bb][0] + krow * 128 + (kbyte ^ c7s));
        a0 = __builtin_amdgcn_mfma_f32_16x16x32_bf16(kf, qf[0][ks], a0, 0, 0, 0);
        a1 = __builtin_amdgcn_mfma_f32_16x16x32_bf16(kf, qf[1][ks], a1, 0, 0, 0);
      }
      st[nt][0] = a0; st[nt][1] = a1;
    }
    __builtin_amdgcn_s_setprio(0);

    const int dw = kv0 - q0 - wid * 32;
    if (dw >= 160 || dw <= -192) {
      const float cb = dw > 0 ? cb_hi : cb_lo;
      #pragma unroll
      for (int nt = 0; nt < 4; ++nt)
        #pragma unroll
        for (int qg = 0; qg < 2; ++qg)
          #pragma unroll
          for (int r = 0; r < 4; ++r) st[nt][qg][r] += cb;
    } else {
      #pragma unroll
      for (int nt = 0; nt < 4; ++nt)
        #pragma unroll
        for (int qg = 0; qg < 2; ++qg) {
          const int base = dw + nt * 16 + g * 4 - qg * 16 - c;
          #pragma unroll
          for (int r = 0; r < 4; ++r) {
            int rel = base + r;
            rel = rel < -128 ? -128 : (rel > 128 ? 128 : rel);
            st[nt][qg][r] += biasc[rel + 128];
          }
        }
    }
    if (mbits & (1u << t)) {
      #pragma unroll
      for (int nt = 0; nt < 4; ++nt)
        #pragma unroll
        for (int r = 0; r < 4; ++r) {
          float mk = kpmb[kv0 + nt * 16 + g * 4 + r] ? -1e30f : 0.f;
          st[nt][0][r] += mk;
          st[nt][1][r] += mk;
        }
    }

    #pragma unroll
    for (int qg = 0; qg < 2; ++qg)
      #pragma unroll
      for (int nt = 0; nt < 4; ++nt) {
        uint2 w;
        w.x = pack_bf16(exp2_fast(st[nt][qg][0]), exp2_fast(st[nt][qg][1]));
        w.y = pack_bf16(exp2_fast(st[nt][qg][2]), exp2_fast(st[nt][qg][3]));
        pw[(qg * 16 + c) * 16 + ((nt * 4 + g) ^ cx)] = w;
      }

    #pragma unroll
    for (int ks = 0; ks < 2; ++ks) {
      const int pu = (ks * 8 + g * 2) ^ cx;
      union { uint2 u[2]; bf16x8 v; } pa0u, pa1u;
      pa0u.u[0] = pw[c * 16 + pu];        pa0u.u[1] = pw[c * 16 + pu + 1];
      pa1u.u[0] = pw[(16 + c) * 16 + pu]; pa1u.u[1] = pw[(16 + c) * 16 + pu + 1];
      const bf16x8 pa0 = pa0u.v, pa1 = pa1u.v;
      l_acc[0] = __builtin_amdgcn_mfma_f32_16x16x32_bf16(pa0, onesf, l_acc[0], 0, 0, 0);
      l_acc[1] = __builtin_amdgcn_mfma_f32_16x16x32_bf16(pa1, onesf, l_acc[1], 0, 0, 0);
      const int pbyte = ks * 64 + g * 16;
      #pragma unroll
      for (int nt = 0; nt < 4; ++nt) {
        int vrow = nt * 16 + c;
        const bf16x8 vf =
            *(const bf16x8*)((const char*)&Vls[bb][0] + vrow * 128 + (pbyte ^ c7s));
        o[nt][0] = __builtin_amdgcn_mfma_f32_16x16x32_bf16(pa0, vf, o[nt][0], 0, 0, 0);
        o[nt][1] = __builtin_amdgcn_mfma_f32_16x16x32_bf16(pa1, vf, o[nt][1], 0, 0, 0);
      }
    }
  }

  #pragma unroll
  for (int qg = 0; qg < 2; ++qg)
    #pragma unroll
    for (int r = 0; r < 4; ++r) {
      float inv = 1.f / l_acc[qg][r];
      int qrow = q0 + wid * 32 + qg * 16 + g * 4 + r;
      size_t obase = ((size_t)b * LSEQ + qrow) * DMODEL + (size_t)h * HD;
      #pragma unroll
      for (int nt = 0; nt < 4; ++nt)
        ob[obase + nt * 16 + c] = f2bf(o[nt][qg][r] * inv);
    }
}

extern "C" void kernel_launch(void* const* d_in, const int* in_sizes, int n_in,
                              void* d_out, int out_size, void* d_ws, size_t ws_size,
                              hipStream_t stream) {
  (void)in_sizes; (void)n_in; (void)out_size; (void)ws_size;
  const float* x = (const float*)d_in[0];
  const unsigned char* kpm = (const unsigned char*)d_in[1];
  const float* Wqkv = (const float*)d_in[2];
  const float* bqkv = (const float*)d_in[3];
  const float* Wout = (const float*)d_in[4];
  const float* bout = (const float*)d_in[5];
  const float* btab = (const float*)d_in[6];
  float* out = (float*)d_out;

  short* ws = (short*)d_ws;
  short* xbf   = ws;
  short* wqkvT = xbf + 4194304;
  short* woutT = wqkvT + 3145728;
  short* qbuf  = woutT + 1048576;
  short* kbuf  = qbuf + 4194304;
  short* vtbuf = kbuf + 4194304;
  short* obuf  = vtbuf + 4194304;

  prep_kernel<<<dim3(8192), dim3(256), 0, stream>>>(x, Wqkv, Wout, xbf, wqkvT, woutT);

  gemm_qkv64<<<dim3(32, 48), dim3(256), 0, stream>>>(xbf, wqkvT, bqkv,
                                                     qbuf, kbuf, vtbuf);
  attn_kernel<<<dim3(512), dim3(256), 0, stream>>>(qbuf, kbuf, vtbuf, kpm, btab, obuf);
  gemm_out64<<<dim3(32, 16), dim3(256), 0, stream>>>(obuf, woutT, bout, out);
}